// Round 6
// baseline (598.223 us; speedup 1.0000x reference)
//
#include <hip/hip_runtime.h>
#include <hip/hip_fp16.h>

#define IN_F 128
#define H 64

#define BKT_BITS 8
#define BKT_SZ 256          // nodes per bucket
#define NBKT_MAX 512        // supports N <= 131072
#define CHUNK 8192          // edges per block in P1/P3

// ---------------- P1: per-bucket edge counts (LDS histogram) ----------------

__global__ void p1_bucket_count(const int* __restrict__ col, int* __restrict__ bucketCnt,
                                int E, int nbkt) {
    __shared__ int h[NBKT_MAX];
    int t = threadIdx.x;
    for (int i = t; i < NBKT_MAX; i += 256) h[i] = 0;
    __syncthreads();
    int beg = blockIdx.x * CHUNK;
    int end = min(E, beg + CHUNK);
    for (int j = beg + t; j < end; j += 256)
        atomicAdd(&h[col[j] >> BKT_BITS], 1);
    __syncthreads();
    for (int i = t; i < nbkt; i += 256)
        if (h[i]) atomicAdd(&bucketCnt[i], h[i]);
}

// ---------------- P2: scan bucket counts -> bases + cursors (1 block) ----------------

__global__ void p2_bucket_scan(const int* __restrict__ bucketCnt, int* __restrict__ base,
                               int* __restrict__ cursor, int nbkt) {
    __shared__ int s[NBKT_MAX];
    int t = threadIdx.x;  // 512 threads
    int v = (t < nbkt) ? bucketCnt[t] : 0;
    s[t] = v;
    __syncthreads();
    for (int off = 1; off < NBKT_MAX; off <<= 1) {
        int tmp = (t >= off) ? s[t - off] : 0;
        __syncthreads();
        s[t] += tmp;
        __syncthreads();
    }
    if (t < nbkt) {
        int b = s[t] - v;  // exclusive
        base[t] = b;
        cursor[t] = b;
    }
    if (t == nbkt - 1) base[nbkt] = s[t];  // == E
}

// ---------------- P3: partition edges into bucket-contiguous (row,col) ----------------

__global__ void p3_partition(const int* __restrict__ row, const int* __restrict__ col,
                             int* __restrict__ cursor, int2* __restrict__ part,
                             int E, int nbkt) {
    __shared__ int h[NBKT_MAX];
    __shared__ int res[NBKT_MAX];
    int t = threadIdx.x;
    for (int i = t; i < NBKT_MAX; i += 256) h[i] = 0;
    __syncthreads();
    int beg = blockIdx.x * CHUNK;
    int end = min(E, beg + CHUNK);
    for (int j = beg + t; j < end; j += 256)
        atomicAdd(&h[col[j] >> BKT_BITS], 1);
    __syncthreads();
    // one reservation atomic per (block, bucket)
    for (int i = t; i < nbkt; i += 256) {
        int c = h[i];
        res[i] = c ? atomicAdd(&cursor[i], c) : 0;
    }
    __syncthreads();
    for (int i = t; i < NBKT_MAX; i += 256) h[i] = 0;  // reuse as local cursor
    __syncthreads();
    for (int j = beg + t; j < end; j += 256) {
        int c = col[j];
        int b = c >> BKT_BITS;
        int l = atomicAdd(&h[b], 1);
        int2 pr; pr.x = row[j]; pr.y = c;
        part[res[b] + l] = pr;
    }
}

// ---------------- P4: per-bucket CSR finalize (offs, dis, src) ----------------

__global__ void p4_csr(const int2* __restrict__ part, const int* __restrict__ base,
                       int* __restrict__ offs, int* __restrict__ srcb,
                       float* __restrict__ dis, int N, int nbkt) {
    __shared__ int deg[BKT_SZ];
    __shared__ int lofs[BKT_SZ];
    __shared__ int cur[BKT_SZ];
    int b = blockIdx.x, t = threadIdx.x;  // 256 threads
    int eb = base[b], ee = base[b + 1];
    deg[t] = 0;
    __syncthreads();
    for (int j = eb + t; j < ee; j += 256)
        atomicAdd(&deg[part[j].y & (BKT_SZ - 1)], 1);
    __syncthreads();
    int v = deg[t];
    lofs[t] = v;
    __syncthreads();
    for (int off = 1; off < BKT_SZ; off <<= 1) {
        int tmp = (t >= off) ? lofs[t - off] : 0;
        __syncthreads();
        lofs[t] += tmp;
        __syncthreads();
    }
    int excl = lofs[t] - v;  // exclusive prefix within bucket
    int g = (b << BKT_BITS) + t;
    if (g < N) {
        offs[g] = eb + excl;
        dis[g] = rsqrtf((float)(v + 1));  // +1 self-loop
    }
    if (b == nbkt - 1 && t == 0) offs[N] = ee;  // == E
    deg[t] = excl;  // repurpose: scatter base per local node
    cur[t] = 0;
    __syncthreads();
    for (int j = eb + t; j < ee; j += 256) {
        int2 pr = part[j];
        int loc = pr.y & (BKT_SZ - 1);
        int l = atomicAdd(&cur[loc], 1);
        srcb[eb + deg[loc] + l] = pr.x;  // within-bucket region: L2 write-combined
    }
}

// ---------------- dense GEMMs: register-resident W column, grid-stride, no LDS ----------

// out[r,:] = half( dis[r] * (x[r,:] @ W) )    x:[N,128] W:[128,64]
// lane owns column c = t&63; W column kept in 128 VGPRs (fully unrolled static idx).
__global__ __launch_bounds__(256) void mm1(const float* __restrict__ x,
                                           const float* __restrict__ W,
                                           const float* __restrict__ dis,
                                           __half* __restrict__ out, int N) {
    int t = threadIdx.x;
    int c = t & 63, rq = t >> 6;
    float wc[IN_F];
#pragma unroll
    for (int k = 0; k < IN_F; ++k) wc[k] = W[k * H + c];
    int ntile = (N + 15) >> 4;
    for (int tile = blockIdx.x; tile < ntile; tile += gridDim.x) {
        int r0 = tile * 16 + rq * 4;
        if (r0 >= N) continue;
        // clamp row indices for safe loads at the tail; stores are predicated
        int rr1 = min(r0 + 1, N - 1), rr2 = min(r0 + 2, N - 1), rr3 = min(r0 + 3, N - 1);
        const float* x0 = x + (size_t)r0 * IN_F;
        const float* x1 = x + (size_t)rr1 * IN_F;
        const float* x2 = x + (size_t)rr2 * IN_F;
        const float* x3 = x + (size_t)rr3 * IN_F;
        float a0 = 0, a1 = 0, a2 = 0, a3 = 0;
#pragma unroll
        for (int k = 0; k < IN_F; k += 4) {
            float4 v0 = *(const float4*)(x0 + k);
            float4 v1 = *(const float4*)(x1 + k);
            float4 v2 = *(const float4*)(x2 + k);
            float4 v3 = *(const float4*)(x3 + k);
            a0 += v0.x * wc[k] + v0.y * wc[k + 1] + v0.z * wc[k + 2] + v0.w * wc[k + 3];
            a1 += v1.x * wc[k] + v1.y * wc[k + 1] + v1.z * wc[k + 2] + v1.w * wc[k + 3];
            a2 += v2.x * wc[k] + v2.y * wc[k + 1] + v2.z * wc[k + 2] + v2.w * wc[k + 3];
            a3 += v3.x * wc[k] + v3.y * wc[k + 1] + v3.z * wc[k + 2] + v3.w * wc[k + 3];
        }
        __half* o = out + (size_t)r0 * H + c;
        o[0] = __float2half(dis[r0] * a0);
        if (r0 + 1 < N) o[H]     = __float2half(dis[rr1] * a1);
        if (r0 + 2 < N) o[2 * H] = __float2half(dis[rr2] * a2);
        if (r0 + 3 < N) o[3 * H] = __float2half(dis[rr3] * a3);
    }
}

// out[r,:] = half( dis[r] * (relu(hin[r,:] + b) @ W) )   hin f32, W:[64,64]
__global__ __launch_bounds__(256) void mm2(const float* __restrict__ hin,
                                           const float* __restrict__ b,
                                           const float* __restrict__ W,
                                           const float* __restrict__ dis,
                                           __half* __restrict__ out, int N) {
    int t = threadIdx.x;
    int c = t & 63, rq = t >> 6;
    float wc[H];
    float bb[H];
#pragma unroll
    for (int k = 0; k < H; ++k) wc[k] = W[k * H + c];
#pragma unroll
    for (int k = 0; k < H; ++k) bb[k] = b[k];  // uniform address -> scalar regs
    int ntile = (N + 15) >> 4;
    for (int tile = blockIdx.x; tile < ntile; tile += gridDim.x) {
        int r0 = tile * 16 + rq * 4;
        if (r0 >= N) continue;
        int rr1 = min(r0 + 1, N - 1), rr2 = min(r0 + 2, N - 1), rr3 = min(r0 + 3, N - 1);
        const float* h0 = hin + (size_t)r0 * H;
        const float* h1 = hin + (size_t)rr1 * H;
        const float* h2 = hin + (size_t)rr2 * H;
        const float* h3 = hin + (size_t)rr3 * H;
        float a0 = 0, a1 = 0, a2 = 0, a3 = 0;
#pragma unroll
        for (int k = 0; k < H; k += 4) {
            float4 v0 = *(const float4*)(h0 + k);
            float4 v1 = *(const float4*)(h1 + k);
            float4 v2 = *(const float4*)(h2 + k);
            float4 v3 = *(const float4*)(h3 + k);
            v0.x = fmaxf(v0.x + bb[k], 0.f);     v0.y = fmaxf(v0.y + bb[k + 1], 0.f);
            v0.z = fmaxf(v0.z + bb[k + 2], 0.f); v0.w = fmaxf(v0.w + bb[k + 3], 0.f);
            v1.x = fmaxf(v1.x + bb[k], 0.f);     v1.y = fmaxf(v1.y + bb[k + 1], 0.f);
            v1.z = fmaxf(v1.z + bb[k + 2], 0.f); v1.w = fmaxf(v1.w + bb[k + 3], 0.f);
            v2.x = fmaxf(v2.x + bb[k], 0.f);     v2.y = fmaxf(v2.y + bb[k + 1], 0.f);
            v2.z = fmaxf(v2.z + bb[k + 2], 0.f); v2.w = fmaxf(v2.w + bb[k + 3], 0.f);
            v3.x = fmaxf(v3.x + bb[k], 0.f);     v3.y = fmaxf(v3.y + bb[k + 1], 0.f);
            v3.z = fmaxf(v3.z + bb[k + 2], 0.f); v3.w = fmaxf(v3.w + bb[k + 3], 0.f);
            a0 += v0.x * wc[k] + v0.y * wc[k + 1] + v0.z * wc[k + 2] + v0.w * wc[k + 3];
            a1 += v1.x * wc[k] + v1.y * wc[k + 1] + v1.z * wc[k + 2] + v1.w * wc[k + 3];
            a2 += v2.x * wc[k] + v2.y * wc[k + 1] + v2.z * wc[k + 2] + v2.w * wc[k + 3];
            a3 += v3.x * wc[k] + v3.y * wc[k + 1] + v3.z * wc[k + 2] + v3.w * wc[k + 3];
        }
        __half* o = out + (size_t)r0 * H + c;
        o[0] = __float2half(dis[r0] * a0);
        if (r0 + 1 < N) o[H]     = __float2half(dis[rr1] * a1);
        if (r0 + 2 < N) o[2 * H] = __float2half(dis[rr2] * a2);
        if (r0 + 3 < N) o[3 * H] = __float2half(dis[rr3] * a3);
    }
}

// out[r,:] = dis[r] * ((hin[r,:] + b) @ W)   W:[64,4]  f32 in/out
__global__ void mm3(const float* __restrict__ hin, const float* __restrict__ b,
                    const float* __restrict__ W, const float* __restrict__ dis,
                    float* __restrict__ out, int N) {
    __shared__ float Wl[H * 4];
    __shared__ float bl[H];
    int t = threadIdx.x;
    if (t < H * 4) Wl[t] = W[t];
    if (t < H) bl[t] = b[t];
    __syncthreads();
    int c = t & 3, rr = t >> 2;
    int r = blockIdx.x * 64 + rr;
    if (r >= N) return;
    const float* h0 = hin + (size_t)r * H;
    float a = 0;
    for (int k = 0; k < H; k += 4) {
        float4 v = *(const float4*)(h0 + k);
        a += (v.x + bl[k])     * Wl[k * 4 + c];
        a += (v.y + bl[k + 1]) * Wl[(k + 1) * 4 + c];
        a += (v.z + bl[k + 2]) * Wl[(k + 2) * 4 + c];
        a += (v.w + bl[k + 3]) * Wl[(k + 3) * 4 + c];
    }
    out[(size_t)r * 4 + c] = dis[r] * a;
}

// ---------------- aggregation (gather over CSR) ----------------

// one wave per node, lane = feature. xs fp16, acc f32, out f32.
__global__ void agg64h(const __half* __restrict__ xs, const int* __restrict__ offs,
                       const int* __restrict__ src, const float* __restrict__ dis,
                       float* __restrict__ out, int N) {
    int wid = (blockIdx.x * 256 + threadIdx.x) >> 6;
    int lane = threadIdx.x & 63;
    if (wid >= N) return;
    int beg = offs[wid], end = offs[wid + 1];
    float acc = __half2float(xs[(size_t)wid * 64 + lane]);  // self-loop (pre-scaled)
    int j = beg;
    for (; j + 8 <= end; j += 8) {
        int s0 = src[j], s1 = src[j + 1], s2 = src[j + 2], s3 = src[j + 3];
        int s4 = src[j + 4], s5 = src[j + 5], s6 = src[j + 6], s7 = src[j + 7];
        float v0 = __half2float(xs[(size_t)s0 * 64 + lane]);
        float v1 = __half2float(xs[(size_t)s1 * 64 + lane]);
        float v2 = __half2float(xs[(size_t)s2 * 64 + lane]);
        float v3 = __half2float(xs[(size_t)s3 * 64 + lane]);
        float v4 = __half2float(xs[(size_t)s4 * 64 + lane]);
        float v5 = __half2float(xs[(size_t)s5 * 64 + lane]);
        float v6 = __half2float(xs[(size_t)s6 * 64 + lane]);
        float v7 = __half2float(xs[(size_t)s7 * 64 + lane]);
        acc += v0; acc += v1; acc += v2; acc += v3;
        acc += v4; acc += v5; acc += v6; acc += v7;
    }
    for (; j < end; ++j) acc += __half2float(xs[(size_t)src[j] * 64 + lane]);
    out[(size_t)wid * 64 + lane] = dis[wid] * acc;
}

// one thread per node, 4 features f32; final output: dis[c]*(inner) + b3
__global__ void agg4(const float* __restrict__ xs, const int* __restrict__ offs,
                     const int* __restrict__ src, const float* __restrict__ dis,
                     const float* __restrict__ b, float* __restrict__ out, int N) {
    int i = blockIdx.x * 256 + threadIdx.x;
    if (i >= N) return;
    float4 v = *(const float4*)(xs + (size_t)i * 4);
    float4 acc = v;  // self-loop term
    int beg = offs[i], end = offs[i + 1];
    for (int j = beg; j < end; ++j) {
        float4 m = *(const float4*)(xs + (size_t)src[j] * 4);
        acc.x += m.x; acc.y += m.y; acc.z += m.z; acc.w += m.w;
    }
    float d = dis[i];
    float4 o;
    o.x = b[0] + d * acc.x;
    o.y = b[1] + d * acc.y;
    o.z = b[2] + d * acc.z;
    o.w = b[3] + d * acc.w;
    *(float4*)(out + (size_t)i * 4) = o;
}

// ---------------- host ----------------

extern "C" void kernel_launch(void* const* d_in, const int* in_sizes, int n_in,
                              void* d_out, int out_size, void* d_ws, size_t ws_size,
                              hipStream_t stream) {
    const float* x  = (const float*)d_in[0];
    const int*   ei = (const int*)d_in[1];
    const float* W1 = (const float*)d_in[2];
    const float* b1 = (const float*)d_in[3];
    const float* W2 = (const float*)d_in[4];
    const float* b2 = (const float*)d_in[5];
    const float* W3 = (const float*)d_in[6];
    const float* b3 = (const float*)d_in[7];
    float* out = (float*)d_out;
    (void)n_in; (void)out_size; (void)ws_size;

    const int N = in_sizes[0] / IN_F;
    const int E = in_sizes[1] / 2;
    const int* row = ei;
    const int* col = ei + E;
    const int nbkt = (N + BKT_SZ - 1) >> BKT_BITS;  // 391 for N=100K (<= 512)

    // workspace carve (all 256B-aligned)
    char* w = (char*)d_ws;
    auto carve = [&](size_t bytes) { char* p = w; w += (bytes + 255) & ~(size_t)255; return p; };
    __half* bufAh  = (__half*)carve((size_t)N * H * 2);   // 12.8 MB (fp16 xs)
    float*  bufB   = (float*)carve((size_t)N * H * 4);    // 25.6 MB (agg out, f32)
    float*  bufC   = (float*)carve((size_t)N * 4 * 4);    // 1.6 MB
    float*  dis    = (float*)carve((size_t)N * 4);
    int*    offs   = (int*)carve((size_t)(N + 1) * 4);
    int*    srcb   = (int*)carve((size_t)E * 4);          // 12.8 MB
    int2*   part   = (int2*)carve((size_t)E * 8);         // 25.6 MB
    int*    bktCnt = (int*)carve((size_t)NBKT_MAX * 4);
    int*    bktBas = (int*)carve((size_t)(NBKT_MAX + 1) * 4);
    int*    bktCur = (int*)carve((size_t)NBKT_MAX * 4);

    (void)hipMemsetAsync(bktCnt, 0, (size_t)nbkt * 4, stream);

    int gE = (E + CHUNK - 1) / CHUNK;  // 391
    int gN = (N + 255) / 256;

    p1_bucket_count<<<gE, 256, 0, stream>>>(col, bktCnt, E, nbkt);
    p2_bucket_scan<<<1, NBKT_MAX, 0, stream>>>(bktCnt, bktBas, bktCur, nbkt);
    p3_partition<<<gE, 256, 0, stream>>>(row, col, bktCur, part, E, nbkt);
    p4_csr<<<nbkt, BKT_SZ, 0, stream>>>(part, bktBas, offs, srcb, dis, N, nbkt);

    // layer 1: xs = half(dis .* (x@W1)) ; agg -> f32
    mm1<<<1536, 256, 0, stream>>>(x, W1, dis, bufAh, N);
    agg64h<<<(N + 3) / 4, 256, 0, stream>>>(bufAh, offs, srcb, dis, bufB, N);
    // layer 2: xs = half(dis .* (relu(agg1+b1)@W2)) ; agg -> f32
    mm2<<<1536, 256, 0, stream>>>(bufB, b1, W2, dis, bufAh, N);
    agg64h<<<(N + 3) / 4, 256, 0, stream>>>(bufAh, offs, srcb, dis, bufB, N);
    // layer 3: xs = dis .* ((agg2+b2)@W3) ; agg (+b3) -> out   (f32 throughout)
    mm3<<<(N + 63) / 64, 256, 0, stream>>>(bufB, b2, W3, dis, bufC, N);
    agg4<<<gN, 256, 0, stream>>>(bufC, offs, srcb, dis, b3, out, N);
}

// Round 7
// 365.905 us; speedup vs baseline: 1.6349x; 1.6349x over previous
//
#include <hip/hip_runtime.h>

#define IN_F 128
#define H 64

#define BKT_BITS 8
#define BKT_SZ 256          // nodes per bucket
#define NBKT_MAX 512        // supports N <= 131072
#define CHUNK 8192          // edges per block in P1/P3

using half8 = __attribute__((ext_vector_type(8))) _Float16;
using f32x4 = __attribute__((ext_vector_type(4))) float;

// ---------------- P1: per-bucket edge counts (LDS histogram) ----------------

__global__ void p1_bucket_count(const int* __restrict__ col, int* __restrict__ bucketCnt,
                                int E, int nbkt) {
    __shared__ int h[NBKT_MAX];
    int t = threadIdx.x;
    for (int i = t; i < NBKT_MAX; i += 256) h[i] = 0;
    __syncthreads();
    int beg = blockIdx.x * CHUNK;
    int end = min(E, beg + CHUNK);
    for (int j = beg + t; j < end; j += 256)
        atomicAdd(&h[col[j] >> BKT_BITS], 1);
    __syncthreads();
    for (int i = t; i < nbkt; i += 256)
        if (h[i]) atomicAdd(&bucketCnt[i], h[i]);
}

// ---------------- P2: scan bucket counts -> bases + cursors (1 block) ----------------

__global__ void p2_bucket_scan(const int* __restrict__ bucketCnt, int* __restrict__ base,
                               int* __restrict__ cursor, int nbkt) {
    __shared__ int s[NBKT_MAX];
    int t = threadIdx.x;  // 512 threads
    int v = (t < nbkt) ? bucketCnt[t] : 0;
    s[t] = v;
    __syncthreads();
    for (int off = 1; off < NBKT_MAX; off <<= 1) {
        int tmp = (t >= off) ? s[t - off] : 0;
        __syncthreads();
        s[t] += tmp;
        __syncthreads();
    }
    if (t < nbkt) {
        int b = s[t] - v;  // exclusive
        base[t] = b;
        cursor[t] = b;
    }
    if (t == nbkt - 1) base[nbkt] = s[t];  // == E
}

// ---------------- P3: partition edges into bucket-contiguous (row,col) ----------------

__global__ void p3_partition(const int* __restrict__ row, const int* __restrict__ col,
                             int* __restrict__ cursor, int2* __restrict__ part,
                             int E, int nbkt) {
    __shared__ int h[NBKT_MAX];
    __shared__ int res[NBKT_MAX];
    int t = threadIdx.x;
    for (int i = t; i < NBKT_MAX; i += 256) h[i] = 0;
    __syncthreads();
    int beg = blockIdx.x * CHUNK;
    int end = min(E, beg + CHUNK);
    for (int j = beg + t; j < end; j += 256)
        atomicAdd(&h[col[j] >> BKT_BITS], 1);
    __syncthreads();
    // one reservation atomic per (block, bucket)
    for (int i = t; i < nbkt; i += 256) {
        int c = h[i];
        res[i] = c ? atomicAdd(&cursor[i], c) : 0;
    }
    __syncthreads();
    for (int i = t; i < NBKT_MAX; i += 256) h[i] = 0;  // reuse as local cursor
    __syncthreads();
    for (int j = beg + t; j < end; j += 256) {
        int c = col[j];
        int b = c >> BKT_BITS;
        int l = atomicAdd(&h[b], 1);
        int2 pr; pr.x = row[j]; pr.y = c;
        part[res[b] + l] = pr;
    }
}

// ---------------- P4: per-bucket CSR finalize (offs, dis, src) ----------------

__global__ void p4_csr(const int2* __restrict__ part, const int* __restrict__ base,
                       int* __restrict__ offs, int* __restrict__ srcb,
                       float* __restrict__ dis, int N, int nbkt) {
    __shared__ int deg[BKT_SZ];
    __shared__ int lofs[BKT_SZ];
    __shared__ int cur[BKT_SZ];
    int b = blockIdx.x, t = threadIdx.x;  // 256 threads
    int eb = base[b], ee = base[b + 1];
    deg[t] = 0;
    __syncthreads();
    for (int j = eb + t; j < ee; j += 256)
        atomicAdd(&deg[part[j].y & (BKT_SZ - 1)], 1);
    __syncthreads();
    int v = deg[t];
    lofs[t] = v;
    __syncthreads();
    for (int off = 1; off < BKT_SZ; off <<= 1) {
        int tmp = (t >= off) ? lofs[t - off] : 0;
        __syncthreads();
        lofs[t] += tmp;
        __syncthreads();
    }
    int excl = lofs[t] - v;  // exclusive prefix within bucket
    int g = (b << BKT_BITS) + t;
    if (g < N) {
        offs[g] = eb + excl;
        dis[g] = rsqrtf((float)(v + 1));  // +1 self-loop
    }
    if (b == nbkt - 1 && t == 0) offs[N] = ee;  // == E
    deg[t] = excl;  // repurpose: scatter base per local node
    cur[t] = 0;
    __syncthreads();
    for (int j = eb + t; j < ee; j += 256) {
        int2 pr = part[j];
        int loc = pr.y & (BKT_SZ - 1);
        int l = atomicAdd(&cur[loc], 1);
        srcb[eb + deg[loc] + l] = pr.x;  // within-bucket region: L2 write-combined
    }
}

// ---------------- fp16 prep: x -> xh ; W1,W2 -> transposed fp16 ----------------

__global__ void cvt_x(const float* __restrict__ x, _Float16* __restrict__ xh, long total8) {
    long i = blockIdx.x * 256 + threadIdx.x;
    long stride = (long)gridDim.x * 256;
    for (; i < total8; i += stride) {
        const float* p = x + i * 8;
        float4 a = *(const float4*)p;
        float4 b = *(const float4*)(p + 4);
        half8 h;
        h[0] = (_Float16)a.x; h[1] = (_Float16)a.y; h[2] = (_Float16)a.z; h[3] = (_Float16)a.w;
        h[4] = (_Float16)b.x; h[5] = (_Float16)b.y; h[6] = (_Float16)b.z; h[7] = (_Float16)b.w;
        *(half8*)(xh + i * 8) = h;
    }
}

// WT1[c][k] = W1[k][c] fp16 ; WT2[c][k] = W2[k][c] fp16
__global__ void prep_w(const float* __restrict__ W1, const float* __restrict__ W2,
                       _Float16* __restrict__ WT1, _Float16* __restrict__ WT2) {
    int t = blockIdx.x * 256 + threadIdx.x;
    int stride = gridDim.x * 256;
    for (int i = t; i < IN_F * H; i += stride) {
        int k = i >> 6, c = i & 63;
        WT1[c * IN_F + k] = (_Float16)W1[i];
    }
    for (int i = t; i < H * H; i += stride) {
        int k = i >> 6, c = i & 63;
        WT2[c * H + k] = (_Float16)W2[i];
    }
}

// ---------------- MFMA GEMMs: no LDS, frags direct from global ----------------
// A[m][k]: lane l holds row m=l&15, k=(l>>4)*8+j (8 contiguous halves = 16B load)
// B[k][n]: lane l holds col n=l&15 (from WT row), same k mapping
// C/D:     col=l&15, row=(l>>4)*4+reg   [verified m89/m91]

// out[r,:] = fp16( dis[r] * (xh[r,:] @ W1) )   xh:[N,128] fp16
__global__ __launch_bounds__(256) void mm1_mfma(const _Float16* __restrict__ xh,
                                                const _Float16* __restrict__ WT1,
                                                const float* __restrict__ dis,
                                                _Float16* __restrict__ out, int N) {
    int t = threadIdx.x;
    int w = t >> 6, l = t & 63, lr = l & 15, lg = l >> 4;
    int r0 = blockIdx.x * 64 + w * 16;
    if (r0 >= N) return;
    half8 bfrag[4][4];
#pragma unroll
    for (int ct = 0; ct < 4; ++ct)
#pragma unroll
        for (int ks = 0; ks < 4; ++ks)
            bfrag[ct][ks] = *(const half8*)(WT1 + (size_t)(ct * 16 + lr) * IN_F + ks * 32 + lg * 8);
    int ar = min(r0 + lr, N - 1);  // clamp tail loads; stores predicated
    const _Float16* ap = xh + (size_t)ar * IN_F + lg * 8;
    f32x4 acc0 = {0.f, 0.f, 0.f, 0.f}, acc1 = acc0, acc2 = acc0, acc3 = acc0;
#pragma unroll
    for (int ks = 0; ks < 4; ++ks) {
        half8 a = *(const half8*)(ap + ks * 32);
        acc0 = __builtin_amdgcn_mfma_f32_16x16x32_f16(a, bfrag[0][ks], acc0, 0, 0, 0);
        acc1 = __builtin_amdgcn_mfma_f32_16x16x32_f16(a, bfrag[1][ks], acc1, 0, 0, 0);
        acc2 = __builtin_amdgcn_mfma_f32_16x16x32_f16(a, bfrag[2][ks], acc2, 0, 0, 0);
        acc3 = __builtin_amdgcn_mfma_f32_16x16x32_f16(a, bfrag[3][ks], acc3, 0, 0, 0);
    }
#pragma unroll
    for (int reg = 0; reg < 4; ++reg) {
        int r = r0 + lg * 4 + reg;
        if (r < N) {
            float d = dis[r];
            _Float16* o = out + (size_t)r * H + lr;
            o[0]  = (_Float16)(d * acc0[reg]);
            o[16] = (_Float16)(d * acc1[reg]);
            o[32] = (_Float16)(d * acc2[reg]);
            o[48] = (_Float16)(d * acc3[reg]);
        }
    }
}

// out[r,:] = fp16( dis[r] * (relu(hh[r,:] + b1) @ W2) )   hh:[N,64] fp16
__global__ __launch_bounds__(256) void mm2_mfma(const _Float16* __restrict__ hh,
                                                const float* __restrict__ b1,
                                                const _Float16* __restrict__ WT2,
                                                const float* __restrict__ dis,
                                                _Float16* __restrict__ out, int N) {
    int t = threadIdx.x;
    int w = t >> 6, l = t & 63, lr = l & 15, lg = l >> 4;
    int r0 = blockIdx.x * 64 + w * 16;
    if (r0 >= N) return;
    half8 bfrag[4][2];
#pragma unroll
    for (int ct = 0; ct < 4; ++ct)
#pragma unroll
        for (int ks = 0; ks < 2; ++ks)
            bfrag[ct][ks] = *(const half8*)(WT2 + (size_t)(ct * 16 + lr) * H + ks * 32 + lg * 8);
    float bias0[8], bias1[8];
#pragma unroll
    for (int j = 0; j < 8; ++j) bias0[j] = b1[lg * 8 + j];
#pragma unroll
    for (int j = 0; j < 8; ++j) bias1[j] = b1[32 + lg * 8 + j];
    int ar = min(r0 + lr, N - 1);
    const _Float16* ap = hh + (size_t)ar * H + lg * 8;
    f32x4 acc0 = {0.f, 0.f, 0.f, 0.f}, acc1 = acc0, acc2 = acc0, acc3 = acc0;
#pragma unroll
    for (int ks = 0; ks < 2; ++ks) {
        half8 a = *(const half8*)(ap + ks * 32);
        half8 af;
#pragma unroll
        for (int j = 0; j < 8; ++j) {
            float v = (float)a[j] + (ks ? bias1[j] : bias0[j]);
            af[j] = (_Float16)fmaxf(v, 0.f);
        }
        acc0 = __builtin_amdgcn_mfma_f32_16x16x32_f16(af, bfrag[0][ks], acc0, 0, 0, 0);
        acc1 = __builtin_amdgcn_mfma_f32_16x16x32_f16(af, bfrag[1][ks], acc1, 0, 0, 0);
        acc2 = __builtin_amdgcn_mfma_f32_16x16x32_f16(af, bfrag[2][ks], acc2, 0, 0, 0);
        acc3 = __builtin_amdgcn_mfma_f32_16x16x32_f16(af, bfrag[3][ks], acc3, 0, 0, 0);
    }
#pragma unroll
    for (int reg = 0; reg < 4; ++reg) {
        int r = r0 + lg * 4 + reg;
        if (r < N) {
            float d = dis[r];
            _Float16* o = out + (size_t)r * H + lr;
            o[0]  = (_Float16)(d * acc0[reg]);
            o[16] = (_Float16)(d * acc1[reg]);
            o[32] = (_Float16)(d * acc2[reg]);
            o[48] = (_Float16)(d * acc3[reg]);
        }
    }
}

// out[r,:] = dis[r] * ((hh[r,:] + b) @ W)   W:[64,4]  hh fp16, out f32
__global__ void mm3(const _Float16* __restrict__ hh, const float* __restrict__ b,
                    const float* __restrict__ W, const float* __restrict__ dis,
                    float* __restrict__ out, int N) {
    __shared__ float Wl[H * 4];
    __shared__ float bl[H];
    int t = threadIdx.x;
    if (t < H * 4) Wl[t] = W[t];
    if (t < H) bl[t] = b[t];
    __syncthreads();
    int c = t & 3, rr = t >> 2;
    int r = blockIdx.x * 64 + rr;
    if (r >= N) return;
    const _Float16* h0 = hh + (size_t)r * H;
    float a = 0;
    for (int k = 0; k < H; k += 8) {
        half8 v = *(const half8*)(h0 + k);
#pragma unroll
        for (int j = 0; j < 8; ++j)
            a += ((float)v[j] + bl[k + j]) * Wl[(k + j) * 4 + c];
    }
    out[(size_t)r * 4 + c] = dis[r] * a;
}

// ---------------- aggregation (gather over CSR) ----------------

// one wave per node, lane = feature. xs fp16, acc f32, out fp16 (pre-scaled by dis)
__global__ void agg64h(const _Float16* __restrict__ xs, const int* __restrict__ offs,
                       const int* __restrict__ src, const float* __restrict__ dis,
                       _Float16* __restrict__ out, int N) {
    int wid = (blockIdx.x * 256 + threadIdx.x) >> 6;
    int lane = threadIdx.x & 63;
    if (wid >= N) return;
    int beg = offs[wid], end = offs[wid + 1];
    float acc = (float)xs[(size_t)wid * 64 + lane];  // self-loop (pre-scaled)
    int j = beg;
    for (; j + 8 <= end; j += 8) {
        int s0 = src[j], s1 = src[j + 1], s2 = src[j + 2], s3 = src[j + 3];
        int s4 = src[j + 4], s5 = src[j + 5], s6 = src[j + 6], s7 = src[j + 7];
        float v0 = (float)xs[(size_t)s0 * 64 + lane];
        float v1 = (float)xs[(size_t)s1 * 64 + lane];
        float v2 = (float)xs[(size_t)s2 * 64 + lane];
        float v3 = (float)xs[(size_t)s3 * 64 + lane];
        float v4 = (float)xs[(size_t)s4 * 64 + lane];
        float v5 = (float)xs[(size_t)s5 * 64 + lane];
        float v6 = (float)xs[(size_t)s6 * 64 + lane];
        float v7 = (float)xs[(size_t)s7 * 64 + lane];
        acc += v0; acc += v1; acc += v2; acc += v3;
        acc += v4; acc += v5; acc += v6; acc += v7;
    }
    for (; j < end; ++j) acc += (float)xs[(size_t)src[j] * 64 + lane];
    out[(size_t)wid * 64 + lane] = (_Float16)(dis[wid] * acc);
}

// one thread per node, 4 features f32; final output: dis[c]*(inner) + b3
__global__ void agg4(const float* __restrict__ xs, const int* __restrict__ offs,
                     const int* __restrict__ src, const float* __restrict__ dis,
                     const float* __restrict__ b, float* __restrict__ out, int N) {
    int i = blockIdx.x * 256 + threadIdx.x;
    if (i >= N) return;
    float4 v = *(const float4*)(xs + (size_t)i * 4);
    float4 acc = v;  // self-loop term
    int beg = offs[i], end = offs[i + 1];
    for (int j = beg; j < end; ++j) {
        float4 m = *(const float4*)(xs + (size_t)src[j] * 4);
        acc.x += m.x; acc.y += m.y; acc.z += m.z; acc.w += m.w;
    }
    float d = dis[i];
    float4 o;
    o.x = b[0] + d * acc.x;
    o.y = b[1] + d * acc.y;
    o.z = b[2] + d * acc.z;
    o.w = b[3] + d * acc.w;
    *(float4*)(out + (size_t)i * 4) = o;
}

// ---------------- host ----------------

extern "C" void kernel_launch(void* const* d_in, const int* in_sizes, int n_in,
                              void* d_out, int out_size, void* d_ws, size_t ws_size,
                              hipStream_t stream) {
    const float* x  = (const float*)d_in[0];
    const int*   ei = (const int*)d_in[1];
    const float* W1 = (const float*)d_in[2];
    const float* b1 = (const float*)d_in[3];
    const float* W2 = (const float*)d_in[4];
    const float* b2 = (const float*)d_in[5];
    const float* W3 = (const float*)d_in[6];
    const float* b3 = (const float*)d_in[7];
    float* out = (float*)d_out;
    (void)n_in; (void)out_size; (void)ws_size;

    const int N = in_sizes[0] / IN_F;
    const int E = in_sizes[1] / 2;
    const int* row = ei;
    const int* col = ei + E;
    const int nbkt = (N + BKT_SZ - 1) >> BKT_BITS;  // 391 for N=100K (<= 512)

    // workspace carve (all 256B-aligned)
    char* w = (char*)d_ws;
    auto carve = [&](size_t bytes) { char* p = w; w += (bytes + 255) & ~(size_t)255; return p; };
    _Float16* xh    = (_Float16*)carve((size_t)N * IN_F * 2);  // 25.6 MB
    _Float16* bufX  = (_Float16*)carve((size_t)N * H * 2);     // 12.8 MB (mm out / agg2 in)
    _Float16* bufY  = (_Float16*)carve((size_t)N * H * 2);     // 12.8 MB (agg out / mm in)
    _Float16* WT1   = (_Float16*)carve((size_t)IN_F * H * 2);
    _Float16* WT2   = (_Float16*)carve((size_t)H * H * 2);
    float*  bufC   = (float*)carve((size_t)N * 4 * 4);         // 1.6 MB
    float*  dis    = (float*)carve((size_t)N * 4);
    int*    offs   = (int*)carve((size_t)(N + 1) * 4);
    int*    srcb   = (int*)carve((size_t)E * 4);               // 12.8 MB
    int2*   part   = (int2*)carve((size_t)E * 8);              // 25.6 MB
    int*    bktCnt = (int*)carve((size_t)NBKT_MAX * 4);
    int*    bktBas = (int*)carve((size_t)(NBKT_MAX + 1) * 4);
    int*    bktCur = (int*)carve((size_t)NBKT_MAX * 4);

    (void)hipMemsetAsync(bktCnt, 0, (size_t)nbkt * 4, stream);

    int gE = (E + CHUNK - 1) / CHUNK;  // 391
    int gN = (N + 255) / 256;
    int gMM = (N + 63) / 64;           // 1563

    p1_bucket_count<<<gE, 256, 0, stream>>>(col, bktCnt, E, nbkt);
    p2_bucket_scan<<<1, NBKT_MAX, 0, stream>>>(bktCnt, bktBas, bktCur, nbkt);
    p3_partition<<<gE, 256, 0, stream>>>(row, col, bktCur, part, E, nbkt);
    p4_csr<<<nbkt, BKT_SZ, 0, stream>>>(part, bktBas, offs, srcb, dis, N, nbkt);

    prep_w<<<48, 256, 0, stream>>>(W1, W2, WT1, WT2);
    cvt_x<<<2048, 256, 0, stream>>>(x, xh, (long)N * IN_F / 8);

    // layer 1: bufX = fp16(dis .* (xh@W1)) ; agg -> bufY fp16
    mm1_mfma<<<gMM, 256, 0, stream>>>(xh, WT1, dis, bufX, N);
    agg64h<<<(N + 3) / 4, 256, 0, stream>>>(bufX, offs, srcb, dis, bufY, N);
    // layer 2: bufX = fp16(dis .* (relu(bufY+b1)@W2)) ; agg -> bufY fp16
    mm2_mfma<<<gMM, 256, 0, stream>>>(bufY, b1, WT2, dis, bufX, N);
    agg64h<<<(N + 3) / 4, 256, 0, stream>>>(bufX, offs, srcb, dis, bufY, N);
    // layer 3: bufC = dis .* ((bufY+b2)@W3) ; agg (+b3) -> out
    mm3<<<gMM, 256, 0, stream>>>(bufY, b2, W3, dis, bufC, N);
    agg4<<<gN, 256, 0, stream>>>(bufC, offs, srcb, dis, b3, out, N);
}

// Round 8
// 331.141 us; speedup vs baseline: 1.8066x; 1.1050x over previous
//
#include <hip/hip_runtime.h>

#define IN_F 128
#define H 64

#define BKT_BITS 8
#define BKT_SZ 256          // nodes per bucket
#define NBKT_MAX 512        // supports N <= 131072
#define CHUNK 8192          // edges per block in P1/P3

using half8 = __attribute__((ext_vector_type(8))) _Float16;
using half2v = __attribute__((ext_vector_type(2))) _Float16;
using f32x4 = __attribute__((ext_vector_type(4))) float;

// ---------------- P1: per-bucket edge counts (LDS histogram) ----------------

__global__ void p1_bucket_count(const int* __restrict__ col, int* __restrict__ bucketCnt,
                                int E, int nbkt) {
    __shared__ int h[NBKT_MAX];
    int t = threadIdx.x;
    for (int i = t; i < NBKT_MAX; i += 256) h[i] = 0;
    __syncthreads();
    int beg = blockIdx.x * CHUNK;
    int end = min(E, beg + CHUNK);
    for (int j = beg + t; j < end; j += 256)
        atomicAdd(&h[col[j] >> BKT_BITS], 1);
    __syncthreads();
    for (int i = t; i < nbkt; i += 256)
        if (h[i]) atomicAdd(&bucketCnt[i], h[i]);
}

// ---------------- P2: scan bucket counts -> bases + cursors (1 block) ----------------

__global__ void p2_bucket_scan(const int* __restrict__ bucketCnt, int* __restrict__ base,
                               int* __restrict__ cursor, int nbkt) {
    __shared__ int s[NBKT_MAX];
    int t = threadIdx.x;  // 512 threads
    int v = (t < nbkt) ? bucketCnt[t] : 0;
    s[t] = v;
    __syncthreads();
    for (int off = 1; off < NBKT_MAX; off <<= 1) {
        int tmp = (t >= off) ? s[t - off] : 0;
        __syncthreads();
        s[t] += tmp;
        __syncthreads();
    }
    if (t < nbkt) {
        int b = s[t] - v;  // exclusive
        base[t] = b;
        cursor[t] = b;
    }
    if (t == nbkt - 1) base[nbkt] = s[t];  // == E
}

// ---------------- P3: partition edges into bucket-contiguous (row,col) ----------------

__global__ void p3_partition(const int* __restrict__ row, const int* __restrict__ col,
                             int* __restrict__ cursor, int2* __restrict__ part,
                             int E, int nbkt) {
    __shared__ int h[NBKT_MAX];
    __shared__ int res[NBKT_MAX];
    int t = threadIdx.x;
    for (int i = t; i < NBKT_MAX; i += 256) h[i] = 0;
    __syncthreads();
    int beg = blockIdx.x * CHUNK;
    int end = min(E, beg + CHUNK);
    for (int j = beg + t; j < end; j += 256)
        atomicAdd(&h[col[j] >> BKT_BITS], 1);
    __syncthreads();
    // one reservation atomic per (block, bucket)
    for (int i = t; i < nbkt; i += 256) {
        int c = h[i];
        res[i] = c ? atomicAdd(&cursor[i], c) : 0;
    }
    __syncthreads();
    for (int i = t; i < NBKT_MAX; i += 256) h[i] = 0;  // reuse as local cursor
    __syncthreads();
    for (int j = beg + t; j < end; j += 256) {
        int c = col[j];
        int b = c >> BKT_BITS;
        int l = atomicAdd(&h[b], 1);
        int2 pr; pr.x = row[j]; pr.y = c;
        part[res[b] + l] = pr;
    }
}

// ---------------- P4: per-bucket CSR finalize (offs, dis, src) ----------------

__global__ void p4_csr(const int2* __restrict__ part, const int* __restrict__ base,
                       int* __restrict__ offs, int* __restrict__ srcb,
                       float* __restrict__ dis, int N, int nbkt) {
    __shared__ int deg[BKT_SZ];
    __shared__ int lofs[BKT_SZ];
    __shared__ int cur[BKT_SZ];
    int b = blockIdx.x, t = threadIdx.x;  // 256 threads
    int eb = base[b], ee = base[b + 1];
    deg[t] = 0;
    __syncthreads();
    for (int j = eb + t; j < ee; j += 256)
        atomicAdd(&deg[part[j].y & (BKT_SZ - 1)], 1);
    __syncthreads();
    int v = deg[t];
    lofs[t] = v;
    __syncthreads();
    for (int off = 1; off < BKT_SZ; off <<= 1) {
        int tmp = (t >= off) ? lofs[t - off] : 0;
        __syncthreads();
        lofs[t] += tmp;
        __syncthreads();
    }
    int excl = lofs[t] - v;  // exclusive prefix within bucket
    int g = (b << BKT_BITS) + t;
    if (g < N) {
        offs[g] = eb + excl;
        dis[g] = rsqrtf((float)(v + 1));  // +1 self-loop
    }
    if (b == nbkt - 1 && t == 0) offs[N] = ee;  // == E
    deg[t] = excl;  // repurpose: scatter base per local node
    cur[t] = 0;
    __syncthreads();
    for (int j = eb + t; j < ee; j += 256) {
        int2 pr = part[j];
        int loc = pr.y & (BKT_SZ - 1);
        int l = atomicAdd(&cur[loc], 1);
        srcb[eb + deg[loc] + l] = pr.x;  // within-bucket region: L2 write-combined
    }
}

// ---------------- fp16 prep: W1,W2 -> transposed fp16 ----------------

// WT1[c][k] = W1[k][c] fp16 ; WT2[c][k] = W2[k][c] fp16
__global__ void prep_w(const float* __restrict__ W1, const float* __restrict__ W2,
                       _Float16* __restrict__ WT1, _Float16* __restrict__ WT2) {
    int t = blockIdx.x * 256 + threadIdx.x;
    int stride = gridDim.x * 256;
    for (int i = t; i < IN_F * H; i += stride) {
        int k = i >> 6, c = i & 63;
        WT1[c * IN_F + k] = (_Float16)W1[i];
    }
    for (int i = t; i < H * H; i += stride) {
        int k = i >> 6, c = i & 63;
        WT2[c * H + k] = (_Float16)W2[i];
    }
}

// ---------------- MFMA GEMMs: no LDS, frags direct from global ----------------
// A[m][k]: lane l holds row m=l&15, k=(l>>4)*8+j (8 contiguous = 16B load)
// B[k][n]: lane l holds col n=l&15 (from WT row), same k mapping
// C/D:     col=l&15, row=(l>>4)*4+reg   [verified m89/m91]

// out[r,:] = fp16( dis[r] * (x[r,:] @ W1) )   x:[N,128] f32, converted in-register
__global__ __launch_bounds__(256) void mm1_mfma(const float* __restrict__ x,
                                                const _Float16* __restrict__ WT1,
                                                const float* __restrict__ dis,
                                                _Float16* __restrict__ out, int N) {
    int t = threadIdx.x;
    int w = t >> 6, l = t & 63, lr = l & 15, lg = l >> 4;
    int r0 = blockIdx.x * 64 + w * 16;
    if (r0 >= N) return;
    half8 bfrag[4][4];
#pragma unroll
    for (int ct = 0; ct < 4; ++ct)
#pragma unroll
        for (int ks = 0; ks < 4; ++ks)
            bfrag[ct][ks] = *(const half8*)(WT1 + (size_t)(ct * 16 + lr) * IN_F + ks * 32 + lg * 8);
    int ar = min(r0 + lr, N - 1);  // clamp tail loads; stores predicated
    const float* ap = x + (size_t)ar * IN_F + lg * 8;
    f32x4 acc0 = {0.f, 0.f, 0.f, 0.f}, acc1 = acc0, acc2 = acc0, acc3 = acc0;
#pragma unroll
    for (int ks = 0; ks < 4; ++ks) {
        float4 a0 = *(const float4*)(ap + ks * 32);
        float4 a1 = *(const float4*)(ap + ks * 32 + 4);
        half8 a;
        a[0] = (_Float16)a0.x; a[1] = (_Float16)a0.y; a[2] = (_Float16)a0.z; a[3] = (_Float16)a0.w;
        a[4] = (_Float16)a1.x; a[5] = (_Float16)a1.y; a[6] = (_Float16)a1.z; a[7] = (_Float16)a1.w;
        acc0 = __builtin_amdgcn_mfma_f32_16x16x32_f16(a, bfrag[0][ks], acc0, 0, 0, 0);
        acc1 = __builtin_amdgcn_mfma_f32_16x16x32_f16(a, bfrag[1][ks], acc1, 0, 0, 0);
        acc2 = __builtin_amdgcn_mfma_f32_16x16x32_f16(a, bfrag[2][ks], acc2, 0, 0, 0);
        acc3 = __builtin_amdgcn_mfma_f32_16x16x32_f16(a, bfrag[3][ks], acc3, 0, 0, 0);
    }
#pragma unroll
    for (int reg = 0; reg < 4; ++reg) {
        int r = r0 + lg * 4 + reg;
        if (r < N) {
            float d = dis[r];
            _Float16* o = out + (size_t)r * H + lr;
            o[0]  = (_Float16)(d * acc0[reg]);
            o[16] = (_Float16)(d * acc1[reg]);
            o[32] = (_Float16)(d * acc2[reg]);
            o[48] = (_Float16)(d * acc3[reg]);
        }
    }
}

// out[r,:] = fp16( dis[r] * (relu(hh[r,:] + b1) @ W2) )   hh:[N,64] fp16
__global__ __launch_bounds__(256) void mm2_mfma(const _Float16* __restrict__ hh,
                                                const float* __restrict__ b1,
                                                const _Float16* __restrict__ WT2,
                                                const float* __restrict__ dis,
                                                _Float16* __restrict__ out, int N) {
    int t = threadIdx.x;
    int w = t >> 6, l = t & 63, lr = l & 15, lg = l >> 4;
    int r0 = blockIdx.x * 64 + w * 16;
    if (r0 >= N) return;
    half8 bfrag[4][2];
#pragma unroll
    for (int ct = 0; ct < 4; ++ct)
#pragma unroll
        for (int ks = 0; ks < 2; ++ks)
            bfrag[ct][ks] = *(const half8*)(WT2 + (size_t)(ct * 16 + lr) * H + ks * 32 + lg * 8);
    float bias0[8], bias1[8];
#pragma unroll
    for (int j = 0; j < 8; ++j) bias0[j] = b1[lg * 8 + j];
#pragma unroll
    for (int j = 0; j < 8; ++j) bias1[j] = b1[32 + lg * 8 + j];
    int ar = min(r0 + lr, N - 1);
    const _Float16* ap = hh + (size_t)ar * H + lg * 8;
    f32x4 acc0 = {0.f, 0.f, 0.f, 0.f}, acc1 = acc0, acc2 = acc0, acc3 = acc0;
#pragma unroll
    for (int ks = 0; ks < 2; ++ks) {
        half8 a = *(const half8*)(ap + ks * 32);
        half8 af;
#pragma unroll
        for (int j = 0; j < 8; ++j) {
            float v = (float)a[j] + (ks ? bias1[j] : bias0[j]);
            af[j] = (_Float16)fmaxf(v, 0.f);
        }
        acc0 = __builtin_amdgcn_mfma_f32_16x16x32_f16(af, bfrag[0][ks], acc0, 0, 0, 0);
        acc1 = __builtin_amdgcn_mfma_f32_16x16x32_f16(af, bfrag[1][ks], acc1, 0, 0, 0);
        acc2 = __builtin_amdgcn_mfma_f32_16x16x32_f16(af, bfrag[2][ks], acc2, 0, 0, 0);
        acc3 = __builtin_amdgcn_mfma_f32_16x16x32_f16(af, bfrag[3][ks], acc3, 0, 0, 0);
    }
#pragma unroll
    for (int reg = 0; reg < 4; ++reg) {
        int r = r0 + lg * 4 + reg;
        if (r < N) {
            float d = dis[r];
            _Float16* o = out + (size_t)r * H + lr;
            o[0]  = (_Float16)(d * acc0[reg]);
            o[16] = (_Float16)(d * acc1[reg]);
            o[32] = (_Float16)(d * acc2[reg]);
            o[48] = (_Float16)(d * acc3[reg]);
        }
    }
}

// out[r,:] = dis[r] * ((hh[r,:] + b) @ W)   W:[64,4]  hh fp16, out f32
__global__ void mm3(const _Float16* __restrict__ hh, const float* __restrict__ b,
                    const float* __restrict__ W, const float* __restrict__ dis,
                    float* __restrict__ out, int N) {
    __shared__ float Wl[H * 4];
    __shared__ float bl[H];
    int t = threadIdx.x;
    if (t < H * 4) Wl[t] = W[t];
    if (t < H) bl[t] = b[t];
    __syncthreads();
    int c = t & 3, rr = t >> 2;
    int r = blockIdx.x * 64 + rr;
    if (r >= N) return;
    const _Float16* h0 = hh + (size_t)r * H;
    float a = 0;
    for (int k = 0; k < H; k += 8) {
        half8 v = *(const half8*)(h0 + k);
#pragma unroll
        for (int j = 0; j < 8; ++j)
            a += ((float)v[j] + bl[k + j]) * Wl[(k + j) * 4 + c];
    }
    out[(size_t)r * 4 + c] = dis[r] * a;
}

// ---------------- aggregation (gather over CSR) ----------------

// one wave per node; lane = (edge-slot es = lane>>5, half2-feature f2 = lane&31).
// Each load instruction gathers TWO edges' rows (32 lanes x 4B = 128B per row).
// xs fp16 (pre-scaled), acc f32, out fp16: out[c,:] = dis[c]*(xs[c,:] + sum xs[src,:])
__global__ void agg64h(const _Float16* __restrict__ xs, const int* __restrict__ offs,
                       const int* __restrict__ src, const float* __restrict__ dis,
                       _Float16* __restrict__ out, int N) {
    int wid = (blockIdx.x * 256 + threadIdx.x) >> 6;
    int lane = threadIdx.x & 63;
    if (wid >= N) return;
    int es = lane >> 5;   // edge slot 0/1
    int f2 = lane & 31;   // half2 index (features 2*f2, 2*f2+1)
    int beg = offs[wid], end = offs[wid + 1];
    const _Float16* base = xs + (size_t)f2 * 2;
    float ax = 0.f, ay = 0.f;
    int j = beg + es;
    // 8 edges per slot in flight -> 16 edges per wave iteration
    for (; j + 14 < end; j += 16) {
        int s0 = src[j],      s1 = src[j + 2],  s2 = src[j + 4],  s3 = src[j + 6];
        int s4 = src[j + 8],  s5 = src[j + 10], s6 = src[j + 12], s7 = src[j + 14];
        half2v v0 = *(const half2v*)(base + (size_t)s0 * 64);
        half2v v1 = *(const half2v*)(base + (size_t)s1 * 64);
        half2v v2 = *(const half2v*)(base + (size_t)s2 * 64);
        half2v v3 = *(const half2v*)(base + (size_t)s3 * 64);
        half2v v4 = *(const half2v*)(base + (size_t)s4 * 64);
        half2v v5 = *(const half2v*)(base + (size_t)s5 * 64);
        half2v v6 = *(const half2v*)(base + (size_t)s6 * 64);
        half2v v7 = *(const half2v*)(base + (size_t)s7 * 64);
        ax += (float)v0[0]; ay += (float)v0[1];
        ax += (float)v1[0]; ay += (float)v1[1];
        ax += (float)v2[0]; ay += (float)v2[1];
        ax += (float)v3[0]; ay += (float)v3[1];
        ax += (float)v4[0]; ay += (float)v4[1];
        ax += (float)v5[0]; ay += (float)v5[1];
        ax += (float)v6[0]; ay += (float)v6[1];
        ax += (float)v7[0]; ay += (float)v7[1];
    }
    for (; j < end; j += 2) {
        half2v v = *(const half2v*)(base + (size_t)src[j] * 64);
        ax += (float)v[0]; ay += (float)v[1];
    }
    // combine the two edge slots (lane ^ 32)
    ax += __shfl_xor(ax, 32);
    ay += __shfl_xor(ay, 32);
    if (es == 0) {
        half2v sv = *(const half2v*)(base + (size_t)wid * 64);  // self-loop term
        float d = dis[wid];
        half2v o;
        o[0] = (_Float16)(d * ((float)sv[0] + ax));
        o[1] = (_Float16)(d * ((float)sv[1] + ay));
        *(half2v*)(out + (size_t)wid * 64 + f2 * 2) = o;
    }
}

// one thread per node, 4 features f32; final output: dis[c]*(inner) + b3
__global__ void agg4(const float* __restrict__ xs, const int* __restrict__ offs,
                     const int* __restrict__ src, const float* __restrict__ dis,
                     const float* __restrict__ b, float* __restrict__ out, int N) {
    int i = blockIdx.x * 256 + threadIdx.x;
    if (i >= N) return;
    float4 v = *(const float4*)(xs + (size_t)i * 4);
    float4 acc = v;  // self-loop term
    int beg = offs[i], end = offs[i + 1];
    for (int j = beg; j < end; ++j) {
        float4 m = *(const float4*)(xs + (size_t)src[j] * 4);
        acc.x += m.x; acc.y += m.y; acc.z += m.z; acc.w += m.w;
    }
    float d = dis[i];
    float4 o;
    o.x = b[0] + d * acc.x;
    o.y = b[1] + d * acc.y;
    o.z = b[2] + d * acc.z;
    o.w = b[3] + d * acc.w;
    *(float4*)(out + (size_t)i * 4) = o;
}

// ---------------- host ----------------

extern "C" void kernel_launch(void* const* d_in, const int* in_sizes, int n_in,
                              void* d_out, int out_size, void* d_ws, size_t ws_size,
                              hipStream_t stream) {
    const float* x  = (const float*)d_in[0];
    const int*   ei = (const int*)d_in[1];
    const float* W1 = (const float*)d_in[2];
    const float* b1 = (const float*)d_in[3];
    const float* W2 = (const float*)d_in[4];
    const float* b2 = (const float*)d_in[5];
    const float* W3 = (const float*)d_in[6];
    const float* b3 = (const float*)d_in[7];
    float* out = (float*)d_out;
    (void)n_in; (void)out_size; (void)ws_size;

    const int N = in_sizes[0] / IN_F;
    const int E = in_sizes[1] / 2;
    const int* row = ei;
    const int* col = ei + E;
    const int nbkt = (N + BKT_SZ - 1) >> BKT_BITS;  // 391 for N=100K (<= 512)

    // workspace carve (all 256B-aligned)
    char* w = (char*)d_ws;
    auto carve = [&](size_t bytes) { char* p = w; w += (bytes + 255) & ~(size_t)255; return p; };
    _Float16* bufX  = (_Float16*)carve((size_t)N * H * 2);     // 12.8 MB (mm out / agg in)
    _Float16* bufY  = (_Float16*)carve((size_t)N * H * 2);     // 12.8 MB (agg out / mm in)
    _Float16* WT1   = (_Float16*)carve((size_t)IN_F * H * 2);
    _Float16* WT2   = (_Float16*)carve((size_t)H * H * 2);
    float*  bufC   = (float*)carve((size_t)N * 4 * 4);         // 1.6 MB
    float*  dis    = (float*)carve((size_t)N * 4);
    int*    offs   = (int*)carve((size_t)(N + 1) * 4);
    int*    srcb   = (int*)carve((size_t)E * 4);               // 12.8 MB
    int2*   part   = (int2*)carve((size_t)E * 8);              // 25.6 MB
    int*    bktCnt = (int*)carve((size_t)NBKT_MAX * 4);
    int*    bktBas = (int*)carve((size_t)(NBKT_MAX + 1) * 4);
    int*    bktCur = (int*)carve((size_t)NBKT_MAX * 4);

    (void)hipMemsetAsync(bktCnt, 0, (size_t)nbkt * 4, stream);

    int gE = (E + CHUNK - 1) / CHUNK;  // 391
    int gN = (N + 255) / 256;
    int gMM = (N + 63) / 64;           // 1563

    p1_bucket_count<<<gE, 256, 0, stream>>>(col, bktCnt, E, nbkt);
    p2_bucket_scan<<<1, NBKT_MAX, 0, stream>>>(bktCnt, bktBas, bktCur, nbkt);
    p3_partition<<<gE, 256, 0, stream>>>(row, col, bktCur, part, E, nbkt);
    p4_csr<<<nbkt, BKT_SZ, 0, stream>>>(part, bktBas, offs, srcb, dis, N, nbkt);

    prep_w<<<48, 256, 0, stream>>>(W1, W2, WT1, WT2);

    // layer 1: bufX = fp16(dis .* (x@W1)) ; agg -> bufY fp16
    mm1_mfma<<<gMM, 256, 0, stream>>>(x, WT1, dis, bufX, N);
    agg64h<<<(N + 3) / 4, 256, 0, stream>>>(bufX, offs, srcb, dis, bufY, N);
    // layer 2: bufX = fp16(dis .* (relu(bufY+b1)@W2)) ; agg -> bufY fp16
    mm2_mfma<<<gMM, 256, 0, stream>>>(bufY, b1, WT2, dis, bufX, N);
    agg64h<<<(N + 3) / 4, 256, 0, stream>>>(bufX, offs, srcb, dis, bufY, N);
    // layer 3: bufC = dis .* ((bufY+b2)@W3) ; agg (+b3) -> out
    mm3<<<gMM, 256, 0, stream>>>(bufY, b2, W3, dis, bufC, N);
    agg4<<<gN, 256, 0, stream>>>(bufC, offs, srcb, dis, b3, out, N);
}

// Round 9
// 310.919 us; speedup vs baseline: 1.9240x; 1.0650x over previous
//
#include <hip/hip_runtime.h>

#define IN_F 128
#define H 64

#define BKT_BITS 8
#define BKT_SZ 256          // nodes per bucket
#define NBKT_MAX 512        // supports N <= 131072
#define CHUNK 8192          // edges per block in P1/P3

using half8 = __attribute__((ext_vector_type(8))) _Float16;
using half4 = __attribute__((ext_vector_type(4))) _Float16;
using f32x4 = __attribute__((ext_vector_type(4))) float;

// ---------------- P1: per-bucket edge counts (LDS histogram) ----------------

__global__ void p1_bucket_count(const int* __restrict__ col, int* __restrict__ bucketCnt,
                                int E, int nbkt) {
    __shared__ int h[NBKT_MAX];
    int t = threadIdx.x;
    for (int i = t; i < NBKT_MAX; i += 256) h[i] = 0;
    __syncthreads();
    int beg = blockIdx.x * CHUNK;
    int end = min(E, beg + CHUNK);
    for (int j = beg + t; j < end; j += 256)
        atomicAdd(&h[col[j] >> BKT_BITS], 1);
    __syncthreads();
    for (int i = t; i < nbkt; i += 256)
        if (h[i]) atomicAdd(&bucketCnt[i], h[i]);
}

// ---------------- P2: scan bucket counts -> bases + cursors (1 block) ----------------

__global__ void p2_bucket_scan(const int* __restrict__ bucketCnt, int* __restrict__ base,
                               int* __restrict__ cursor, int nbkt) {
    __shared__ int s[NBKT_MAX];
    int t = threadIdx.x;  // 512 threads
    int v = (t < nbkt) ? bucketCnt[t] : 0;
    s[t] = v;
    __syncthreads();
    for (int off = 1; off < NBKT_MAX; off <<= 1) {
        int tmp = (t >= off) ? s[t - off] : 0;
        __syncthreads();
        s[t] += tmp;
        __syncthreads();
    }
    if (t < nbkt) {
        int b = s[t] - v;  // exclusive
        base[t] = b;
        cursor[t] = b;
    }
    if (t == nbkt - 1) base[nbkt] = s[t];  // == E
}

// ---------------- P3: partition edges, packed (loc<<24 | row) ----------------

__global__ void p3_partition(const int* __restrict__ row, const int* __restrict__ col,
                             int* __restrict__ cursor, int* __restrict__ part,
                             int E, int nbkt) {
    __shared__ int h[NBKT_MAX];
    __shared__ int res[NBKT_MAX];
    int t = threadIdx.x;
    for (int i = t; i < NBKT_MAX; i += 256) h[i] = 0;
    __syncthreads();
    int beg = blockIdx.x * CHUNK;
    int end = min(E, beg + CHUNK);
    for (int j = beg + t; j < end; j += 256)
        atomicAdd(&h[col[j] >> BKT_BITS], 1);
    __syncthreads();
    // one reservation atomic per (block, bucket)
    for (int i = t; i < nbkt; i += 256) {
        int c = h[i];
        res[i] = c ? atomicAdd(&cursor[i], c) : 0;
    }
    __syncthreads();
    for (int i = t; i < NBKT_MAX; i += 256) h[i] = 0;  // reuse as local cursor
    __syncthreads();
    for (int j = beg + t; j < end; j += 256) {
        int c = col[j];
        int b = c >> BKT_BITS;
        int l = atomicAdd(&h[b], 1);
        int pk = (int)(((unsigned)(c & (BKT_SZ - 1)) << 24) | (unsigned)row[j]);  // row < 2^24
        part[res[b] + l] = pk;
    }
}

// ---------------- P4: per-bucket CSR finalize (offs, dis, src) ----------------

__global__ void p4_csr(const int* __restrict__ part, const int* __restrict__ base,
                       int* __restrict__ offs, int* __restrict__ srcb,
                       float* __restrict__ dis, int N, int nbkt) {
    __shared__ int deg[BKT_SZ];
    __shared__ int lofs[BKT_SZ];
    __shared__ int cur[BKT_SZ];
    int b = blockIdx.x, t = threadIdx.x;  // 256 threads
    int eb = base[b], ee = base[b + 1];
    deg[t] = 0;
    __syncthreads();
    for (int j = eb + t; j < ee; j += 256)
        atomicAdd(&deg[(unsigned)part[j] >> 24], 1);
    __syncthreads();
    int v = deg[t];
    lofs[t] = v;
    __syncthreads();
    for (int off = 1; off < BKT_SZ; off <<= 1) {
        int tmp = (t >= off) ? lofs[t - off] : 0;
        __syncthreads();
        lofs[t] += tmp;
        __syncthreads();
    }
    int excl = lofs[t] - v;  // exclusive prefix within bucket
    int g = (b << BKT_BITS) + t;
    if (g < N) {
        offs[g] = eb + excl;
        dis[g] = rsqrtf((float)(v + 1));  // +1 self-loop
    }
    if (b == nbkt - 1 && t == 0) offs[N] = ee;  // == E
    deg[t] = excl;  // repurpose: scatter base per local node
    cur[t] = 0;
    __syncthreads();
    for (int j = eb + t; j < ee; j += 256) {
        int pk = part[j];
        int loc = (unsigned)pk >> 24;
        int l = atomicAdd(&cur[loc], 1);
        srcb[eb + deg[loc] + l] = pk & 0xFFFFFF;  // within-bucket region: L2 write-combined
    }
}

// ---------------- fp16 prep: W1,W2 -> transposed fp16 ----------------

// WT1[c][k] = W1[k][c] fp16 ; WT2[c][k] = W2[k][c] fp16
__global__ void prep_w(const float* __restrict__ W1, const float* __restrict__ W2,
                       _Float16* __restrict__ WT1, _Float16* __restrict__ WT2) {
    int t = blockIdx.x * 256 + threadIdx.x;
    int stride = gridDim.x * 256;
    for (int i = t; i < IN_F * H; i += stride) {
        int k = i >> 6, c = i & 63;
        WT1[c * IN_F + k] = (_Float16)W1[i];
    }
    for (int i = t; i < H * H; i += stride) {
        int k = i >> 6, c = i & 63;
        WT2[c * H + k] = (_Float16)W2[i];
    }
}

// ---------------- MFMA GEMMs: no LDS, frags direct from global ----------------
// A[m][k]: lane l holds row m=l&15, k=(l>>4)*8+j (8 contiguous = 16B load)
// B[k][n]: lane l holds col n=l&15 (from WT row), same k mapping
// C/D:     col=l&15, row=(l>>4)*4+reg   [verified m89/m91]

// out[r,:] = fp16( dis[r] * (x[r,:] @ W1) )   x:[N,128] f32, converted in-register
__global__ __launch_bounds__(256) void mm1_mfma(const float* __restrict__ x,
                                                const _Float16* __restrict__ WT1,
                                                const float* __restrict__ dis,
                                                _Float16* __restrict__ out, int N) {
    int t = threadIdx.x;
    int w = t >> 6, l = t & 63, lr = l & 15, lg = l >> 4;
    int r0 = blockIdx.x * 64 + w * 16;
    if (r0 >= N) return;
    half8 bfrag[4][4];
#pragma unroll
    for (int ct = 0; ct < 4; ++ct)
#pragma unroll
        for (int ks = 0; ks < 4; ++ks)
            bfrag[ct][ks] = *(const half8*)(WT1 + (size_t)(ct * 16 + lr) * IN_F + ks * 32 + lg * 8);
    int ar = min(r0 + lr, N - 1);  // clamp tail loads; stores predicated
    const float* ap = x + (size_t)ar * IN_F + lg * 8;
    f32x4 acc0 = {0.f, 0.f, 0.f, 0.f}, acc1 = acc0, acc2 = acc0, acc3 = acc0;
#pragma unroll
    for (int ks = 0; ks < 4; ++ks) {
        float4 a0 = *(const float4*)(ap + ks * 32);
        float4 a1 = *(const float4*)(ap + ks * 32 + 4);
        half8 a;
        a[0] = (_Float16)a0.x; a[1] = (_Float16)a0.y; a[2] = (_Float16)a0.z; a[3] = (_Float16)a0.w;
        a[4] = (_Float16)a1.x; a[5] = (_Float16)a1.y; a[6] = (_Float16)a1.z; a[7] = (_Float16)a1.w;
        acc0 = __builtin_amdgcn_mfma_f32_16x16x32_f16(a, bfrag[0][ks], acc0, 0, 0, 0);
        acc1 = __builtin_amdgcn_mfma_f32_16x16x32_f16(a, bfrag[1][ks], acc1, 0, 0, 0);
        acc2 = __builtin_amdgcn_mfma_f32_16x16x32_f16(a, bfrag[2][ks], acc2, 0, 0, 0);
        acc3 = __builtin_amdgcn_mfma_f32_16x16x32_f16(a, bfrag[3][ks], acc3, 0, 0, 0);
    }
#pragma unroll
    for (int reg = 0; reg < 4; ++reg) {
        int r = r0 + lg * 4 + reg;
        if (r < N) {
            float d = dis[r];
            _Float16* o = out + (size_t)r * H + lr;
            o[0]  = (_Float16)(d * acc0[reg]);
            o[16] = (_Float16)(d * acc1[reg]);
            o[32] = (_Float16)(d * acc2[reg]);
            o[48] = (_Float16)(d * acc3[reg]);
        }
    }
}

// out[r,:] = fp16( dis[r] * (relu(hh[r,:] + b1) @ W2) )   hh:[N,64] fp16
__global__ __launch_bounds__(256) void mm2_mfma(const _Float16* __restrict__ hh,
                                                const float* __restrict__ b1,
                                                const _Float16* __restrict__ WT2,
                                                const float* __restrict__ dis,
                                                _Float16* __restrict__ out, int N) {
    int t = threadIdx.x;
    int w = t >> 6, l = t & 63, lr = l & 15, lg = l >> 4;
    int r0 = blockIdx.x * 64 + w * 16;
    if (r0 >= N) return;
    half8 bfrag[4][2];
#pragma unroll
    for (int ct = 0; ct < 4; ++ct)
#pragma unroll
        for (int ks = 0; ks < 2; ++ks)
            bfrag[ct][ks] = *(const half8*)(WT2 + (size_t)(ct * 16 + lr) * H + ks * 32 + lg * 8);
    float bias0[8], bias1[8];
#pragma unroll
    for (int j = 0; j < 8; ++j) bias0[j] = b1[lg * 8 + j];
#pragma unroll
    for (int j = 0; j < 8; ++j) bias1[j] = b1[32 + lg * 8 + j];
    int ar = min(r0 + lr, N - 1);
    const _Float16* ap = hh + (size_t)ar * H + lg * 8;
    f32x4 acc0 = {0.f, 0.f, 0.f, 0.f}, acc1 = acc0, acc2 = acc0, acc3 = acc0;
#pragma unroll
    for (int ks = 0; ks < 2; ++ks) {
        half8 a = *(const half8*)(ap + ks * 32);
        half8 af;
#pragma unroll
        for (int j = 0; j < 8; ++j) {
            float v = (float)a[j] + (ks ? bias1[j] : bias0[j]);
            af[j] = (_Float16)fmaxf(v, 0.f);
        }
        acc0 = __builtin_amdgcn_mfma_f32_16x16x32_f16(af, bfrag[0][ks], acc0, 0, 0, 0);
        acc1 = __builtin_amdgcn_mfma_f32_16x16x32_f16(af, bfrag[1][ks], acc1, 0, 0, 0);
        acc2 = __builtin_amdgcn_mfma_f32_16x16x32_f16(af, bfrag[2][ks], acc2, 0, 0, 0);
        acc3 = __builtin_amdgcn_mfma_f32_16x16x32_f16(af, bfrag[3][ks], acc3, 0, 0, 0);
    }
#pragma unroll
    for (int reg = 0; reg < 4; ++reg) {
        int r = r0 + lg * 4 + reg;
        if (r < N) {
            float d = dis[r];
            _Float16* o = out + (size_t)r * H + lr;
            o[0]  = (_Float16)(d * acc0[reg]);
            o[16] = (_Float16)(d * acc1[reg]);
            o[32] = (_Float16)(d * acc2[reg]);
            o[48] = (_Float16)(d * acc3[reg]);
        }
    }
}

// out[r,:] = dis[r] * ((hh[r,:] + b) @ W)   W:[64,4]  hh fp16, out f32
__global__ void mm3(const _Float16* __restrict__ hh, const float* __restrict__ b,
                    const float* __restrict__ W, const float* __restrict__ dis,
                    float* __restrict__ out, int N) {
    __shared__ float Wl[H * 4];
    __shared__ float bl[H];
    int t = threadIdx.x;
    if (t < H * 4) Wl[t] = W[t];
    if (t < H) bl[t] = b[t];
    __syncthreads();
    int c = t & 3, rr = t >> 2;
    int r = blockIdx.x * 64 + rr;
    if (r >= N) return;
    const _Float16* h0 = hh + (size_t)r * H;
    float a = 0;
    for (int k = 0; k < H; k += 8) {
        half8 v = *(const half8*)(h0 + k);
#pragma unroll
        for (int j = 0; j < 8; ++j)
            a += ((float)v[j] + bl[k + j]) * Wl[(k + j) * 4 + c];
    }
    out[(size_t)r * 4 + c] = dis[r] * a;
}

// ---------------- aggregation (gather over CSR) ----------------

// one wave per node; lane = (slot s = lane>>4, feature-quad f = lane&15 -> 8B).
// Per 32-edge iter: ONE coalesced index load + 8 bpermute + 8 gather instrs
// (each gather: 4 rows x 128B = 512B). 32 edges in flight per wave.
// xs fp16 (pre-scaled), acc f32, out fp16: out[c,:] = dis[c]*(xs[c,:] + sum xs[src,:])
__global__ void agg64h(const _Float16* __restrict__ xs, const int* __restrict__ offs,
                       const int* __restrict__ src, const float* __restrict__ dis,
                       _Float16* __restrict__ out, int N) {
    int wid = (blockIdx.x * 256 + threadIdx.x) >> 6;
    int lane = threadIdx.x & 63;
    if (wid >= N) return;
    int s = lane >> 4;   // slot 0..3 (8 edges each per iter)
    int f = lane & 15;   // feature quad: halves [4f, 4f+4)
    int beg = offs[wid], end = offs[wid + 1];
    int deg = end - beg;
    const _Float16* base = xs + (size_t)f * 4;
    float a0 = 0.f, a1 = 0.f, a2 = 0.f, a3 = 0.f;
    int nfull = deg >> 5;
    int j = beg;
    for (int it = 0; it < nfull; ++it, j += 32) {
        int idx = src[j + (lane & 31)];  // one coalesced load: 32 indices
#pragma unroll
        for (int k = 0; k < 8; ++k) {
            int sk = __shfl(idx, s * 8 + k);
            half4 v = *(const half4*)(base + (size_t)sk * 64);
            a0 += (float)v[0]; a1 += (float)v[1]; a2 += (float)v[2]; a3 += (float)v[3];
        }
    }
    for (int jj = j + s; jj < end; jj += 4) {  // tail: slots round-robin
        int sk = src[jj];
        half4 v = *(const half4*)(base + (size_t)sk * 64);
        a0 += (float)v[0]; a1 += (float)v[1]; a2 += (float)v[2]; a3 += (float)v[3];
    }
    // combine the 4 slots
    a0 += __shfl_xor(a0, 16); a0 += __shfl_xor(a0, 32);
    a1 += __shfl_xor(a1, 16); a1 += __shfl_xor(a1, 32);
    a2 += __shfl_xor(a2, 16); a2 += __shfl_xor(a2, 32);
    a3 += __shfl_xor(a3, 16); a3 += __shfl_xor(a3, 32);
    if (s == 0) {
        half4 sv = *(const half4*)(base + (size_t)wid * 64);  // self-loop term
        float d = dis[wid];
        half4 o;
        o[0] = (_Float16)(d * ((float)sv[0] + a0));
        o[1] = (_Float16)(d * ((float)sv[1] + a1));
        o[2] = (_Float16)(d * ((float)sv[2] + a2));
        o[3] = (_Float16)(d * ((float)sv[3] + a3));
        *(half4*)(out + (size_t)wid * 64 + f * 4) = o;
    }
}

// one thread per node, 4 features f32; final output: dis[c]*(inner) + b3
__global__ void agg4(const float* __restrict__ xs, const int* __restrict__ offs,
                     const int* __restrict__ src, const float* __restrict__ dis,
                     const float* __restrict__ b, float* __restrict__ out, int N) {
    int i = blockIdx.x * 256 + threadIdx.x;
    if (i >= N) return;
    float4 v = *(const float4*)(xs + (size_t)i * 4);
    float4 acc = v;  // self-loop term
    int beg = offs[i], end = offs[i + 1];
    int j = beg;
    for (; j + 3 < end; j += 4) {
        int s0 = src[j], s1 = src[j + 1], s2 = src[j + 2], s3 = src[j + 3];
        float4 m0 = *(const float4*)(xs + (size_t)s0 * 4);
        float4 m1 = *(const float4*)(xs + (size_t)s1 * 4);
        float4 m2 = *(const float4*)(xs + (size_t)s2 * 4);
        float4 m3 = *(const float4*)(xs + (size_t)s3 * 4);
        acc.x += m0.x + m1.x + m2.x + m3.x;
        acc.y += m0.y + m1.y + m2.y + m3.y;
        acc.z += m0.z + m1.z + m2.z + m3.z;
        acc.w += m0.w + m1.w + m2.w + m3.w;
    }
    for (; j < end; ++j) {
        float4 m = *(const float4*)(xs + (size_t)src[j] * 4);
        acc.x += m.x; acc.y += m.y; acc.z += m.z; acc.w += m.w;
    }
    float d = dis[i];
    float4 o;
    o.x = b[0] + d * acc.x;
    o.y = b[1] + d * acc.y;
    o.z = b[2] + d * acc.z;
    o.w = b[3] + d * acc.w;
    *(float4*)(out + (size_t)i * 4) = o;
}

// ---------------- host ----------------

extern "C" void kernel_launch(void* const* d_in, const int* in_sizes, int n_in,
                              void* d_out, int out_size, void* d_ws, size_t ws_size,
                              hipStream_t stream) {
    const float* x  = (const float*)d_in[0];
    const int*   ei = (const int*)d_in[1];
    const float* W1 = (const float*)d_in[2];
    const float* b1 = (const float*)d_in[3];
    const float* W2 = (const float*)d_in[4];
    const float* b2 = (const float*)d_in[5];
    const float* W3 = (const float*)d_in[6];
    const float* b3 = (const float*)d_in[7];
    float* out = (float*)d_out;
    (void)n_in; (void)out_size; (void)ws_size;

    const int N = in_sizes[0] / IN_F;
    const int E = in_sizes[1] / 2;
    const int* row = ei;
    const int* col = ei + E;
    const int nbkt = (N + BKT_SZ - 1) >> BKT_BITS;  // 391 for N=100K (<= 512)

    // workspace carve (all 256B-aligned)
    char* w = (char*)d_ws;
    auto carve = [&](size_t bytes) { char* p = w; w += (bytes + 255) & ~(size_t)255; return p; };
    _Float16* bufX  = (_Float16*)carve((size_t)N * H * 2);     // 12.8 MB (mm out / agg in)
    _Float16* bufY  = (_Float16*)carve((size_t)N * H * 2);     // 12.8 MB (agg out / mm in)
    _Float16* WT1   = (_Float16*)carve((size_t)IN_F * H * 2);
    _Float16* WT2   = (_Float16*)carve((size_t)H * H * 2);
    float*  bufC   = (float*)carve((size_t)N * 4 * 4);         // 1.6 MB
    float*  dis    = (float*)carve((size_t)N * 4);
    int*    offs   = (int*)carve((size_t)(N + 1) * 4);
    int*    srcb   = (int*)carve((size_t)E * 4);               // 12.8 MB
    int*    part   = (int*)carve((size_t)E * 4);               // 12.8 MB (packed loc|row)
    int*    bktCnt = (int*)carve((size_t)NBKT_MAX * 4);
    int*    bktBas = (int*)carve((size_t)(NBKT_MAX + 1) * 4);
    int*    bktCur = (int*)carve((size_t)NBKT_MAX * 4);

    (void)hipMemsetAsync(bktCnt, 0, (size_t)nbkt * 4, stream);

    int gE = (E + CHUNK - 1) / CHUNK;  // 391
    int gN = (N + 255) / 256;
    int gMM = (N + 63) / 64;           // 1563

    p1_bucket_count<<<gE, 256, 0, stream>>>(col, bktCnt, E, nbkt);
    p2_bucket_scan<<<1, NBKT_MAX, 0, stream>>>(bktCnt, bktBas, bktCur, nbkt);
    p3_partition<<<gE, 256, 0, stream>>>(row, col, bktCur, part, E, nbkt);
    p4_csr<<<nbkt, BKT_SZ, 0, stream>>>(part, bktBas, offs, srcb, dis, N, nbkt);

    prep_w<<<48, 256, 0, stream>>>(W1, W2, WT1, WT2);

    // layer 1: bufX = fp16(dis .* (x@W1)) ; agg -> bufY fp16
    mm1_mfma<<<gMM, 256, 0, stream>>>(x, WT1, dis, bufX, N);
    agg64h<<<(N + 3) / 4, 256, 0, stream>>>(bufX, offs, srcb, dis, bufY, N);
    // layer 2: bufX = fp16(dis .* (relu(bufY+b1)@W2)) ; agg -> bufY fp16
    mm2_mfma<<<gMM, 256, 0, stream>>>(bufY, b1, WT2, dis, bufX, N);
    agg64h<<<(N + 3) / 4, 256, 0, stream>>>(bufX, offs, srcb, dis, bufY, N);
    // layer 3: bufC = dis .* ((bufY+b2)@W3) ; agg (+b3) -> out
    mm3<<<gMM, 256, 0, stream>>>(bufY, b2, W3, dis, bufC, N);
    agg4<<<gN, 256, 0, stream>>>(bufC, offs, srcb, dis, b3, out, N);
}